// Round 7
// baseline (385.916 us; speedup 1.0000x reference)
//
#include <hip/hip_runtime.h>
#include <cstdint>
#include <cstddef>

#define B_ 2
#define S_ 2048
#define D_ 2048
#define H_ 32
#define KV_ 8
#define HD_ 64
#define M_ (B_*S_)      // 4096 rows total
#define EQ_ (H_*HD_)    // 2048
#define EK_ (KV_*HD_)   // 512

typedef unsigned short u16;
typedef __attribute__((ext_vector_type(8))) short s16x8;   // 8 x bf16 (4 VGPRs)
typedef __attribute__((ext_vector_type(4))) float f32x4;

// q pre-scale folds 1/sqrt(HD)=0.125 and log2(e) so flash uses raw 2^x
#define QSCALE 0.18033688011112042f      // 0.125 * log2(e)
#define EXPOFF 15.869645449778564f       // 11 * log2(e)

#if __has_builtin(__builtin_amdgcn_exp2f)
#define EXP2(x) __builtin_amdgcn_exp2f(x)
#else
#define EXP2(x) __expf((x) * 0.6931471805599453f)
#endif

__device__ __forceinline__ u16 f2bf(float f) {
  unsigned u = __float_as_uint(f);
  u += 0x7fffu + ((u >> 16) & 1u);        // RNE
  return (u16)(u >> 16);
}
// pack two floats to two bf16 in one dword via v_perm (proven path)
__device__ __forceinline__ unsigned pk2(float a, float b) {
  unsigned ua = __float_as_uint(a) + 0x8000u;
  unsigned ub = __float_as_uint(b) + 0x8000u;
  return __builtin_amdgcn_perm(ub, ua, 0x07060302);  // [ua.b2,ua.b3,ub.b2,ub.b3]
}
__device__ __forceinline__ f32x4 mfma16(s16x8 a, s16x8 b, f32x4 c) {
  return __builtin_amdgcn_mfma_f32_16x16x32_bf16(a, b, c, 0, 0, 0);
}
__device__ __forceinline__ void gl_lds16(const void* g, void* l) {
  __builtin_amdgcn_global_load_lds(
      (const __attribute__((address_space(1))) void*)g,
      (__attribute__((address_space(3))) void*)l, 16, 0, 0);
}

// ---------------- fused fp32 -> bf16 cast of all 5 inputs ----------------
__global__ void cast_all(const float4* __restrict__ x, const float4* __restrict__ wq,
                         const float4* __restrict__ wk, const float4* __restrict__ wv,
                         const float4* __restrict__ wo, ushort4* __restrict__ dst) {
  int i = blockIdx.x * 256 + threadIdx.x;
  const float4* src; int off;
  if (i < 2097152)      { src = x;  off = i; }
  else if (i < 3145728) { src = wq; off = i - 2097152; }
  else if (i < 3407872) { src = wk; off = i - 3145728; }
  else if (i < 3670016) { src = wv; off = i - 3407872; }
  else                  { src = wo; off = i - 3670016; }
  float4 v = src[off];
  ushort4 r;
  r.x = f2bf(v.x); r.y = f2bf(v.y); r.z = f2bf(v.z); r.w = f2bf(v.w);
  dst[i] = r;
}

// ---------------- fused QKV projection GEMM (BK=64, XOR-swizzled LDS) ----------------
// (unchanged from R6 — 89 us, 0 bank conflicts)
__global__ __launch_bounds__(256)
void gemm_qkv(const u16* __restrict__ A, const u16* __restrict__ Bw,
              u16* __restrict__ qb, u16* __restrict__ kb, u16* __restrict__ vtb,
              const float* __restrict__ fc) {
  __shared__ __align__(16) u16 As[128 * 64];
  __shared__ __align__(16) u16 Bs[128 * 64];
  const int tid  = threadIdx.x;
  const int lane = tid & 63;
  const int wave = tid >> 6;
  const int m0 = blockIdx.y * 128;
  const int n0 = blockIdx.x * 128;
  const int wm = (wave >> 1) * 64;
  const int wn = (wave & 1) * 64;
  const int l15 = lane & 15;
  const int quad = lane >> 4;

  f32x4 acc[4][4] = {};

  for (int k0 = 0; k0 < D_; k0 += 64) {
    #pragma unroll
    for (int rr = 0; rr < 4; ++rr) {
      int c = tid + rr * 256;
      int row = c >> 3;
      int ksrc = ((c & 7) ^ (row & 7)) * 8;
      gl_lds16(A  + (size_t)(m0 + row) * D_ + k0 + ksrc, &As[c * 8]);
      gl_lds16(Bw + (size_t)(n0 + row) * D_ + k0 + ksrc, &Bs[c * 8]);
    }
    __syncthreads();

    #pragma unroll
    for (int kc = 0; kc < 2; ++kc) {
      s16x8 af[4], bfr[4];
      #pragma unroll
      for (int mi = 0; mi < 4; ++mi) {
        int row = wm + mi * 16 + l15;
        af[mi]  = *(const s16x8*)&As[row * 64 + (((kc * 4 + quad) ^ (row & 7)) * 8)];
      }
      #pragma unroll
      for (int ni = 0; ni < 4; ++ni) {
        int row = wn + ni * 16 + l15;
        bfr[ni] = *(const s16x8*)&Bs[row * 64 + (((kc * 4 + quad) ^ (row & 7)) * 8)];
      }
      #pragma unroll
      for (int mi = 0; mi < 4; ++mi)
        #pragma unroll
        for (int ni = 0; ni < 4; ++ni)
          acc[mi][ni] = mfma16(af[mi], bfr[ni], acc[mi][ni]);
    }
    __syncthreads();
  }

  if (n0 < 2560) {
    const bool isQ = (n0 < 2048);
    u16* dst = isQ ? qb : kb;
    const int ncol0 = isQ ? 0 : 2048;
    const int ndim  = isQ ? EQ_ : EK_;
    const float scale = isQ ? QSCALE : 1.0f;
    const float sg = (l15 & 1) ? 1.f : -1.f;
    #pragma unroll
    for (int mi = 0; mi < 4; ++mi) {
      #pragma unroll
      for (int r = 0; r < 4; ++r) {
        int row = m0 + wm + mi * 16 + quad * 4 + r;
        const float* fr = fc + (size_t)(row & (S_ - 1)) * 64;
        #pragma unroll
        for (int ni = 0; ni < 4; ++ni) {
          int col = n0 + wn + ni * 16 + l15;
          int ip = (col & 63) >> 1;
          float c  = fr[ip * 2];
          float sn = fr[ip * 2 + 1];
          float v = acc[mi][ni][r];
          float p = __shfl_xor(v, 1, 64);
          float o = (v * c + sg * (p * sn)) * scale;
          dst[(size_t)row * ndim + col - ncol0] = f2bf(o);
        }
      }
    }
  } else {
    #pragma unroll
    for (int mi = 0; mi < 4; ++mi) {
      #pragma unroll
      for (int ni = 0; ni < 4; ++ni) {
        int vcol = n0 + wn + ni * 16 + l15 - 2560;
        uint2 w;
        w.x = pk2(acc[mi][ni][0], acc[mi][ni][1]);
        w.y = pk2(acc[mi][ni][2], acc[mi][ni][3]);
        *(uint2*)(vtb + (size_t)vcol * M_ + m0 + wm + mi * 16 + quad * 4) = w;
      }
    }
  }
}

// ---------------- O-projection GEMM: 512 threads, 128x128 tile, BK=64 ----------------
// 8 waves as 2x4: wave covers rows (wave>>2)*64..+63, cols (wave&3)*32..+31.
__global__ __launch_bounds__(512)
void gemm_o(const u16* __restrict__ A, const u16* __restrict__ Bw, float* __restrict__ C,
            int Ndim, int Kdim) {
  __shared__ __align__(16) u16 As[128 * 64];
  __shared__ __align__(16) u16 Bs[128 * 64];
  const int tid  = threadIdx.x;
  const int lane = tid & 63;
  const int wave = tid >> 6;
  const int m0 = blockIdx.y * 128;
  const int n0 = blockIdx.x * 128;
  const int wm = (wave >> 2) * 64;
  const int wn = (wave & 3) * 32;
  const int l15 = lane & 15;
  const int quad = lane >> 4;

  f32x4 acc[4][2] = {};

  for (int k0 = 0; k0 < Kdim; k0 += 64) {
    #pragma unroll
    for (int rr = 0; rr < 2; ++rr) {
      int c = tid + rr * 512;
      int row = c >> 3;
      int ksrc = ((c & 7) ^ (row & 7)) * 8;
      gl_lds16(A  + (size_t)(m0 + row) * Kdim + k0 + ksrc, &As[c * 8]);
      gl_lds16(Bw + (size_t)(n0 + row) * Kdim + k0 + ksrc, &Bs[c * 8]);
    }
    __syncthreads();

    #pragma unroll
    for (int kc = 0; kc < 2; ++kc) {
      s16x8 af[4], bfr[2];
      #pragma unroll
      for (int mi = 0; mi < 4; ++mi) {
        int row = wm + mi * 16 + l15;
        af[mi]  = *(const s16x8*)&As[row * 64 + (((kc * 4 + quad) ^ (row & 7)) * 8)];
      }
      #pragma unroll
      for (int ni = 0; ni < 2; ++ni) {
        int row = wn + ni * 16 + l15;
        bfr[ni] = *(const s16x8*)&Bs[row * 64 + (((kc * 4 + quad) ^ (row & 7)) * 8)];
      }
      #pragma unroll
      for (int mi = 0; mi < 4; ++mi)
        #pragma unroll
        for (int ni = 0; ni < 2; ++ni)
          acc[mi][ni] = mfma16(af[mi], bfr[ni], acc[mi][ni]);
    }
    __syncthreads();
  }

  #pragma unroll
  for (int mi = 0; mi < 4; ++mi) {
    #pragma unroll
    for (int r = 0; r < 4; ++r) {
      int row = m0 + wm + mi * 16 + quad * 4 + r;
      size_t base = (size_t)row * Ndim + n0 + wn;
      #pragma unroll
      for (int ni = 0; ni < 2; ++ni)
        C[base + ni * 16 + l15] = acc[mi][ni][r];
    }
  }
}

// ---------------- causal GQA flash attention v5: uniform 17-round double-queue ----------------
// Fixed-max softmax => k-tiles are independent => block bx's 33 tile-visits
// (lo-tile bx: bx+1 visits; hi-tile 31-bx: 32-bx visits) split into two
// queues of 17/16 processed 2-per-round. EVERY block runs exactly 17 rounds
// of 32 dense MFMAs (no drain tail, no half-empty rounds). V double-buffered
// in LDS (slot = queue, staged by wave-pairs); K frags read direct from
// global (L2-resident, reused by 64 blocks); per-wave P buffer reused across
// the two visits (DS in-order within a wave).
__global__ __launch_bounds__(256, 4)
void flash_attn(const u16* __restrict__ qb, const u16* __restrict__ kb,
                const u16* __restrict__ vtb, u16* __restrict__ ob) {
  const int bx = blockIdx.x;        // 0..15
  const int h  = blockIdx.y;
  const int b  = blockIdx.z;
  const int g  = h >> 2;            // REP=4
  const int tid  = threadIdx.x;
  const int lane = tid & 63;
  const int wave = tid >> 6;
  const int l15  = lane & 15;
  const int quad = lane >> 4;
  const int kq   = quad * 8;

  const int Tlo = bx, Thi = 31 - bx;
  const int n_lo = Tlo + 1;                 // 1..16 (always < 17)
  const int rL = Tlo * 64 + wave * 16;
  const int rH = Thi * 64 + wave * 16;
  const int rowL = rL + l15;
  const int rowH = rH + l15;

  __shared__ __align__(16) u16 Vs[2][8 * 512];      // [slot][t-chunk][d-row][8]
  __shared__ __align__(16) u16 Pl[4][16 * 72];      // per-wave, reused per visit

  const u16* kbg  = kb  + (size_t)b * S_ * EK_ + g * HD_;
  const u16* vtbg = vtb + ((size_t)(g * HD_ + lane)) * M_ + b * S_;

  // Q b-frags (lane m = l15): q pre-scaled by 0.125*log2e
  const u16* qpL = qb + (size_t)(b * S_ + rL + l15) * EQ_ + h * HD_;
  const u16* qpH = qb + (size_t)(b * S_ + rH + l15) * EQ_ + h * HD_;
  s16x8 qL0 = *(const s16x8*)(qpL + kq);
  s16x8 qL1 = *(const s16x8*)(qpL + 32 + kq);
  s16x8 qH0 = *(const s16x8*)(qpH + kq);
  s16x8 qH1 = *(const s16x8*)(qpH + 32 + kq);

  f32x4 OL[4] = {}, OH[4] = {};
  float sumL = 0.f, sumH = 0.f;
  u16* pw = &Pl[wave][0];

  // one tile-visit: S^T = K Q^T (K frags from global), mask, exp, P-roundtrip, O += V^T P
  auto visit = [&](int kt, bool msk, const s16x8& qa0, const s16x8& qa1,
                   int qrow, f32x4* O, float& sum, const u16* Vsl) {
    const int t0 = kt * 64;
    f32x4 sc[4];
    #pragma unroll
    for (int ts = 0; ts < 4; ++ts) {
      const u16* kp = kbg + (size_t)(t0 + ts * 16 + l15) * EK_;
      s16x8 k0 = *(const s16x8*)(kp + kq);
      s16x8 k1 = *(const s16x8*)(kp + 32 + kq);
      f32x4 s = {};
      s = mfma16(k0, qa0, s);
      sc[ts] = mfma16(k1, qa1, s);
    }
    #pragma unroll
    for (int ts = 0; ts < 4; ++ts) {
      f32x4 s = sc[ts];
      if (msk) {
        const int tb = t0 + ts * 16 + quad * 4;
        #pragma unroll
        for (int r = 0; r < 4; ++r) if (tb + r > qrow) s[r] = -1e30f;
      }
      float p0 = EXP2(s[0] - EXPOFF), p1 = EXP2(s[1] - EXPOFF);
      float p2 = EXP2(s[2] - EXPOFF), p3 = EXP2(s[3] - EXPOFF);
      sum += (p0 + p1) + (p2 + p3);
      uint2 w; w.x = pk2(p0, p1); w.y = pk2(p2, p3);
      *(uint2*)&pw[l15 * 72 + ts * 16 + quad * 4] = w;
    }
    s16x8 pa0 = *(const s16x8*)&pw[l15 * 72 + kq];
    s16x8 pa1 = *(const s16x8*)&pw[l15 * 72 + 32 + kq];
    #pragma unroll
    for (int df = 0; df < 4; ++df) {
      s16x8 v0 = *(const s16x8*)&Vsl[quad * 512 + (df * 16 + l15) * 8];
      s16x8 v1 = *(const s16x8*)&Vsl[(4 + quad) * 512 + (df * 16 + l15) * 8];
      O[df] = mfma16(v1, pa1, mfma16(v0, pa0, O[df]));
    }
  };

  for (int rd = 0; rd < 17; ++rd) {
    // ---- stage V: waves 0,1 -> slot 0 (visit A = rd), waves 2,3 -> slot 1 (visit B = 17+rd) ----
    {
      const int gs = (wave >> 1) * 17 + rd;
      if (gs < 33) {
        const int rg = (gs >= n_lo) ? 1 : 0;
        const int kt = rg ? gs - n_lo : gs;
        const u16* src = vtbg + kt * 64;
        #pragma unroll
        for (int r = 0; r < 4; ++r) {
          int i = (wave & 1) * 4 + r;
          gl_lds16(src + i * 8, &Vs[wave >> 1][i * 512 + lane * 8]);
        }
      }
    }
    __syncthreads();

    // ---- visit A (g = rd): lo while rd < n_lo, then hi ----
    if (rd < n_lo) visit(rd,        rd == Tlo,          qL0, qL1, rowL, OL, sumL, &Vs[0][0]);
    else           visit(rd - n_lo, rd - n_lo == Thi,   qH0, qH1, rowH, OH, sumH, &Vs[0][0]);

    // ---- visit B (g = 17 + rd): always hi (n_lo <= 16 < 17) ----
    {
      const int gv = 17 + rd;
      if (gv < 33) {
        const int kt = gv - n_lo;
        visit(kt, kt == Thi, qH0, qH1, rowH, OH, sumH, &Vs[1][0]);
      }
    }
    __syncthreads();
  }

  // ---- deferred row-sum reduction (across the 4 quad copies) + store ----
  sumH += __shfl_xor(sumH, 16, 64); sumH += __shfl_xor(sumH, 32, 64);
  sumL += __shfl_xor(sumL, 16, 64); sumL += __shfl_xor(sumL, 32, 64);
  float invH = 1.f / sumH, invL = 1.f / sumL;

  {
    u16* op = ob + (size_t)(b * S_ + rowH) * EQ_ + h * HD_;
    #pragma unroll
    for (int df = 0; df < 4; ++df) {
      uint2 w;
      w.x = pk2(OH[df][0] * invH, OH[df][1] * invH);
      w.y = pk2(OH[df][2] * invH, OH[df][3] * invH);
      *(uint2*)(op + df * 16 + quad * 4) = w;
    }
  }
  {
    u16* op = ob + (size_t)(b * S_ + rowL) * EQ_ + h * HD_;
    #pragma unroll
    for (int df = 0; df < 4; ++df) {
      uint2 w;
      w.x = pk2(OL[df][0] * invL, OL[df][1] * invL);
      w.y = pk2(OL[df][2] * invL, OL[df][3] * invL);
      *(uint2*)(op + df * 16 + quad * 4) = w;
    }
  }
}

extern "C" void kernel_launch(void* const* d_in, const int* in_sizes, int n_in,
                              void* d_out, int out_size, void* d_ws, size_t ws_size,
                              hipStream_t stream) {
  (void)in_sizes; (void)n_in; (void)out_size; (void)ws_size;
  const float* x  = (const float*)d_in[0];
  const float* fc = (const float*)d_in[1];
  const float* wq = (const float*)d_in[2];
  const float* wk = (const float*)d_in[3];
  const float* wv = (const float*)d_in[4];
  const float* wo = (const float*)d_in[5];
  float* out = (float*)d_out;
  char* ws = (char*)d_ws;

  u16* xb  = (u16*)(ws);              // 4096x2048
  u16* wqb = (u16*)(ws + 16777216);   // 2048x2048  } contiguous fused [wq;wk;wv]
  u16* wob = (u16*)(ws + 29360128);   // 2048x2048
  u16* qb  = (u16*)(ws + 37748736);   // 4096x2048  (rope'd, x QSCALE)
  u16* kb  = (u16*)(ws + 54525952);   // 4096x512   (rope'd)
  u16* vtb = (u16*)(ws + 58720256);   // 512x4096   (V^T)
  u16* ob  = (u16*)(ws + 62914560);   // 4096x2048

  cast_all<<<18432, 256, 0, stream>>>((const float4*)x, (const float4*)wq,
                                      (const float4*)wk, (const float4*)wv,
                                      (const float4*)wo, (ushort4*)ws);

  gemm_qkv<<<dim3(24, 32), 256, 0, stream>>>(xb, wqb, qb, kb, vtb, fc);

  flash_attn<<<dim3(16, 32, 2), 256, 0, stream>>>(qb, kb, vtb, ob);

  gemm_o<<<dim3(16, 32), 512, 0, stream>>>(ob, wob, out, D_, EQ_);
}

// Round 8
// 310.251 us; speedup vs baseline: 1.2439x; 1.2439x over previous
//
#include <hip/hip_runtime.h>
#include <cstdint>
#include <cstddef>

#define B_ 2
#define S_ 2048
#define D_ 2048
#define H_ 32
#define KV_ 8
#define HD_ 64
#define M_ (B_*S_)      // 4096 rows total
#define EQ_ (H_*HD_)    // 2048
#define EK_ (KV_*HD_)   // 512

typedef unsigned short u16;
typedef __attribute__((ext_vector_type(8))) short s16x8;   // 8 x bf16 (4 VGPRs)
typedef __attribute__((ext_vector_type(4))) float f32x4;

// q pre-scale folds 1/sqrt(HD)=0.125 and log2(e) so flash uses raw 2^x
#define QSCALE 0.18033688011112042f      // 0.125 * log2(e)
#define EXPOFF 15.869645449778564f       // 11 * log2(e)

#if __has_builtin(__builtin_amdgcn_exp2f)
#define EXP2(x) __builtin_amdgcn_exp2f(x)
#else
#define EXP2(x) __expf((x) * 0.6931471805599453f)
#endif

__device__ __forceinline__ u16 f2bf(float f) {
  unsigned u = __float_as_uint(f);
  u += 0x7fffu + ((u >> 16) & 1u);        // RNE
  return (u16)(u >> 16);
}
// pack two floats to two bf16 in one dword via v_perm (proven path)
__device__ __forceinline__ unsigned pk2(float a, float b) {
  unsigned ua = __float_as_uint(a) + 0x8000u;
  unsigned ub = __float_as_uint(b) + 0x8000u;
  return __builtin_amdgcn_perm(ub, ua, 0x07060302);  // [ua.b2,ua.b3,ub.b2,ub.b3]
}
__device__ __forceinline__ f32x4 mfma16(s16x8 a, s16x8 b, f32x4 c) {
  return __builtin_amdgcn_mfma_f32_16x16x32_bf16(a, b, c, 0, 0, 0);
}
__device__ __forceinline__ void gl_lds16(const void* g, void* l) {
  __builtin_amdgcn_global_load_lds(
      (const __attribute__((address_space(1))) void*)g,
      (__attribute__((address_space(3))) void*)l, 16, 0, 0);
}

// ---------------- fused fp32 -> bf16 cast of all 5 inputs ----------------
__global__ void cast_all(const float4* __restrict__ x, const float4* __restrict__ wq,
                         const float4* __restrict__ wk, const float4* __restrict__ wv,
                         const float4* __restrict__ wo, ushort4* __restrict__ dst) {
  int i = blockIdx.x * 256 + threadIdx.x;
  const float4* src; int off;
  if (i < 2097152)      { src = x;  off = i; }
  else if (i < 3145728) { src = wq; off = i - 2097152; }
  else if (i < 3407872) { src = wk; off = i - 3145728; }
  else if (i < 3670016) { src = wv; off = i - 3407872; }
  else                  { src = wo; off = i - 3670016; }
  float4 v = src[off];
  ushort4 r;
  r.x = f2bf(v.x); r.y = f2bf(v.y); r.z = f2bf(v.z); r.w = f2bf(v.w);
  dst[i] = r;
}

// ---------------- fused QKV projection GEMM: 128x96 tile, BK=64, 4 blocks/CU ----------------
// C[m][n] = sum_k X[m][k] * W[n][k], W = [wq; wk; wv] (N=3072 contiguous).
// Grid (32,32)=1024 blocks = 4/CU. XOR-swizzled LDS (0 bank conflicts, R6-proven).
// Region boundaries (2048, 2560) are 16-multiples -> per-ni branch is wave-uniform.
__global__ __launch_bounds__(256)
void gemm_qkv(const u16* __restrict__ A, const u16* __restrict__ Bw,
              u16* __restrict__ qb, u16* __restrict__ kb, u16* __restrict__ vtb,
              const float* __restrict__ fc) {
  __shared__ __align__(16) u16 As[128 * 64];   // 16 KB
  __shared__ __align__(16) u16 Bs[96 * 64];    // 12 KB
  const int tid  = threadIdx.x;
  const int lane = tid & 63;
  const int wave = tid >> 6;
  const int m0 = blockIdx.y * 128;
  const int n0 = blockIdx.x * 96;
  const int wm = (wave >> 1) * 64;
  const int wn = (wave & 1) * 48;
  const int l15 = lane & 15;
  const int quad = lane >> 4;

  f32x4 acc[4][3] = {};

  for (int k0 = 0; k0 < D_; k0 += 64) {
    #pragma unroll
    for (int rr = 0; rr < 4; ++rr) {
      int c = tid + rr * 256;                 // 0..1023: row=c>>3 (0..127)
      int row = c >> 3;
      int ksrc = ((c & 7) ^ (row & 7)) * 8;
      gl_lds16(A + (size_t)(m0 + row) * D_ + k0 + ksrc, &As[c * 8]);
    }
    #pragma unroll
    for (int rr = 0; rr < 3; ++rr) {
      int c = tid + rr * 256;                 // 0..767: row=c>>3 (0..95)
      int row = c >> 3;
      int ksrc = ((c & 7) ^ (row & 7)) * 8;
      gl_lds16(Bw + (size_t)(n0 + row) * D_ + k0 + ksrc, &Bs[c * 8]);
    }
    __syncthreads();

    #pragma unroll
    for (int kc = 0; kc < 2; ++kc) {
      s16x8 af[4], bfr[3];
      #pragma unroll
      for (int mi = 0; mi < 4; ++mi) {
        int row = wm + mi * 16 + l15;
        af[mi]  = *(const s16x8*)&As[row * 64 + (((kc * 4 + quad) ^ (row & 7)) * 8)];
      }
      #pragma unroll
      for (int ni = 0; ni < 3; ++ni) {
        int row = wn + ni * 16 + l15;
        bfr[ni] = *(const s16x8*)&Bs[row * 64 + (((kc * 4 + quad) ^ (row & 7)) * 8)];
      }
      #pragma unroll
      for (int mi = 0; mi < 4; ++mi)
        #pragma unroll
        for (int ni = 0; ni < 3; ++ni)
          acc[mi][ni] = mfma16(af[mi], bfr[ni], acc[mi][ni]);
    }
    __syncthreads();
  }

  // ---- epilogue: per-ni region branch (wave-uniform) ----
  const float sg = (l15 & 1) ? 1.f : -1.f;
  #pragma unroll
  for (int mi = 0; mi < 4; ++mi) {
    #pragma unroll
    for (int ni = 0; ni < 3; ++ni) {
      const int col = n0 + wn + ni * 16 + l15;
      if (col < 2560) {
        // Q or K: fused RoPE (even lane: tr*c - ti*sn; odd: tr*sn + ti*c)
        const bool isQ = (col < 2048);
        u16* dst = isQ ? qb : kb;
        const int ncol0 = isQ ? 0 : 2048;
        const int ndim  = isQ ? EQ_ : EK_;
        const float scale = isQ ? QSCALE : 1.0f;
        const int ip = (col & 63) >> 1;
        #pragma unroll
        for (int r = 0; r < 4; ++r) {
          int row = m0 + wm + mi * 16 + quad * 4 + r;
          const float* fr = fc + (size_t)(row & (S_ - 1)) * 64;
          float c  = fr[ip * 2];
          float sn = fr[ip * 2 + 1];
          float v = acc[mi][ni][r];
          float p = __shfl_xor(v, 1, 64);
          float o = (v * c + sg * (p * sn)) * scale;
          dst[(size_t)row * ndim + col - ncol0] = f2bf(o);
        }
      } else {
        // V: transposed store, 4 consecutive rows per lane -> one 8B store
        const int vcol = col - 2560;
        uint2 w;
        w.x = pk2(acc[mi][ni][0], acc[mi][ni][1]);
        w.y = pk2(acc[mi][ni][2], acc[mi][ni][3]);
        *(uint2*)(vtb + (size_t)vcol * M_ + m0 + wm + mi * 16 + quad * 4) = w;
      }
    }
  }
}

// ---------------- O-projection GEMM: 64x128 tile, BK=64, 4 blocks/CU ----------------
// Grid (16,64)=1024 blocks. 4 waves as 2x2: wave = 32 rows x 64 cols (acc[2][4]).
__global__ __launch_bounds__(256)
void gemm_o(const u16* __restrict__ A, const u16* __restrict__ Bw, float* __restrict__ C,
            int Ndim, int Kdim) {
  __shared__ __align__(16) u16 As[64 * 64];    // 8 KB
  __shared__ __align__(16) u16 Bs[128 * 64];   // 16 KB
  const int tid  = threadIdx.x;
  const int lane = tid & 63;
  const int wave = tid >> 6;
  const int m0 = blockIdx.y * 64;
  const int n0 = blockIdx.x * 128;
  const int wm = (wave >> 1) * 32;
  const int wn = (wave & 1) * 64;
  const int l15 = lane & 15;
  const int quad = lane >> 4;

  f32x4 acc[2][4] = {};

  for (int k0 = 0; k0 < Kdim; k0 += 64) {
    #pragma unroll
    for (int rr = 0; rr < 2; ++rr) {
      int c = tid + rr * 256;                 // 0..511: row=c>>3 (0..63)
      int row = c >> 3;
      int ksrc = ((c & 7) ^ (row & 7)) * 8;
      gl_lds16(A + (size_t)(m0 + row) * Kdim + k0 + ksrc, &As[c * 8]);
    }
    #pragma unroll
    for (int rr = 0; rr < 4; ++rr) {
      int c = tid + rr * 256;                 // 0..1023: row=c>>3 (0..127)
      int row = c >> 3;
      int ksrc = ((c & 7) ^ (row & 7)) * 8;
      gl_lds16(Bw + (size_t)(n0 + row) * Kdim + k0 + ksrc, &Bs[c * 8]);
    }
    __syncthreads();

    #pragma unroll
    for (int kc = 0; kc < 2; ++kc) {
      s16x8 af[2], bfr[4];
      #pragma unroll
      for (int mi = 0; mi < 2; ++mi) {
        int row = wm + mi * 16 + l15;
        af[mi]  = *(const s16x8*)&As[row * 64 + (((kc * 4 + quad) ^ (row & 7)) * 8)];
      }
      #pragma unroll
      for (int ni = 0; ni < 4; ++ni) {
        int row = wn + ni * 16 + l15;
        bfr[ni] = *(const s16x8*)&Bs[row * 64 + (((kc * 4 + quad) ^ (row & 7)) * 8)];
      }
      #pragma unroll
      for (int mi = 0; mi < 2; ++mi)
        #pragma unroll
        for (int ni = 0; ni < 4; ++ni)
          acc[mi][ni] = mfma16(af[mi], bfr[ni], acc[mi][ni]);
    }
    __syncthreads();
  }

  #pragma unroll
  for (int mi = 0; mi < 2; ++mi) {
    #pragma unroll
    for (int r = 0; r < 4; ++r) {
      int row = m0 + wm + mi * 16 + quad * 4 + r;
      size_t base = (size_t)row * Ndim + n0 + wn;
      #pragma unroll
      for (int ni = 0; ni < 4; ++ni)
        C[base + ni * 16 + l15] = acc[mi][ni][r];
    }
  }
}

// ---------------- causal GQA flash attention v4 (R6-proven, reverted) ----------------
// S^T = K Q^T formulation, fixed-max softmax via raw 2^x (q pre-scaled by
// 0.125*log2e), block-shared K/V via global_load_lds, balanced causal
// pairing (block bx owns q-tiles {bx, 31-bx}).
__global__ __launch_bounds__(256, 4)
void flash_attn(const u16* __restrict__ qb, const u16* __restrict__ kb,
                const u16* __restrict__ vtb, u16* __restrict__ ob) {
  const int bx = blockIdx.x;        // 0..15
  const int h  = blockIdx.y;
  const int b  = blockIdx.z;
  const int g  = h >> 2;            // REP=4
  const int tid  = threadIdx.x;
  const int lane = tid & 63;
  const int wave = tid >> 6;
  const int l15  = lane & 15;
  const int quad = lane >> 4;
  const int kq   = quad * 8;

  const int Tlo = bx, Thi = 31 - bx;
  const int n_lo = Tlo + 1, n_hi = Thi + 1;
  const int rL = Tlo * 64 + wave * 16;
  const int rH = Thi * 64 + wave * 16;
  const int rowL = rL + l15;
  const int rowH = rH + l15;

  __shared__ __align__(16) u16 Ks[8 * 512];
  __shared__ __align__(16) u16 Vs[8 * 512];
  __shared__ __align__(16) u16 Pl[4][2][16 * 72];

  u16* PbL = &Pl[wave][0][0];
  u16* PbH = &Pl[wave][1][0];

  const u16* qpL = qb + (size_t)(b * S_ + rL + l15) * EQ_ + h * HD_;
  const u16* qpH = qb + (size_t)(b * S_ + rH + l15) * EQ_ + h * HD_;
  s16x8 qL0 = *(const s16x8*)(qpL + kq);
  s16x8 qL1 = *(const s16x8*)(qpL + 32 + kq);
  s16x8 qH0 = *(const s16x8*)(qpH + kq);
  s16x8 qH1 = *(const s16x8*)(qpH + 32 + kq);

  f32x4 OL[4] = {}, OH[4] = {};
  float sumL = 0.f, sumH = 0.f;

  const int sw = wave & 1;
  const bool doK = (wave < 2);

  for (int kt = 0; kt < n_hi; ++kt) {
    const int t0 = kt * 64;

    if (doK) {
      const u16* src = kb + (size_t)(b * S_ + t0 + lane) * EK_ + g * HD_;
      #pragma unroll
      for (int r = 0; r < 4; ++r) {
        int i = sw * 4 + r;
        gl_lds16(src + i * 8, &Ks[i * 512 + lane * 8]);
      }
    } else {
      const u16* src = vtb + (size_t)(g * HD_ + lane) * M_ + b * S_ + t0;
      #pragma unroll
      for (int r = 0; r < 4; ++r) {
        int i = sw * 4 + r;
        gl_lds16(src + i * 8, &Vs[i * 512 + lane * 8]);
      }
    }
    __syncthreads();

    const bool do_lo = (kt < n_lo);
    const bool mH = (kt == n_hi - 1);
    const bool mL = (kt == n_lo - 1);

    #pragma unroll
    for (int ts = 0; ts < 4; ++ts) {
      s16x8 k0 = *(const s16x8*)&Ks[quad * 512 + (ts * 16 + l15) * 8];
      s16x8 k1 = *(const s16x8*)&Ks[(4 + quad) * 512 + (ts * 16 + l15) * 8];
      const int tb = t0 + ts * 16 + quad * 4;
      {
        f32x4 s = {};
        s = mfma16(k0, qH0, s);
        s = mfma16(k1, qH1, s);
        if (mH) {
          #pragma unroll
          for (int r = 0; r < 4; ++r) if (tb + r > rowH) s[r] = -1e30f;
        }
        float p0 = EXP2(s[0] - EXPOFF), p1 = EXP2(s[1] - EXPOFF);
        float p2 = EXP2(s[2] - EXPOFF), p3 = EXP2(s[3] - EXPOFF);
        sumH += (p0 + p1) + (p2 + p3);
        uint2 w; w.x = pk2(p0, p1); w.y = pk2(p2, p3);
        *(uint2*)&PbH[l15 * 72 + ts * 16 + quad * 4] = w;
      }
      if (do_lo) {
        f32x4 s = {};
        s = mfma16(k0, qL0, s);
        s = mfma16(k1, qL1, s);
        if (mL) {
          #pragma unroll
          for (int r = 0; r < 4; ++r) if (tb + r > rowL) s[r] = -1e30f;
        }
        float p0 = EXP2(s[0] - EXPOFF), p1 = EXP2(s[1] - EXPOFF);
        float p2 = EXP2(s[2] - EXPOFF), p3 = EXP2(s[3] - EXPOFF);
        sumL += (p0 + p1) + (p2 + p3);
        uint2 w; w.x = pk2(p0, p1); w.y = pk2(p2, p3);
        *(uint2*)&PbL[l15 * 72 + ts * 16 + quad * 4] = w;
      }
    }

    s16x8 pH0 = *(const s16x8*)&PbH[l15 * 72 + kq];
    s16x8 pH1 = *(const s16x8*)&PbH[l15 * 72 + 32 + kq];
    s16x8 pL0 = {}, pL1 = {};
    if (do_lo) {
      pL0 = *(const s16x8*)&PbL[l15 * 72 + kq];
      pL1 = *(const s16x8*)&PbL[l15 * 72 + 32 + kq];
    }

    #pragma unroll
    for (int df = 0; df < 4; ++df) {
      s16x8 v0 = *(const s16x8*)&Vs[quad * 512 + (df * 16 + l15) * 8];
      s16x8 v1 = *(const s16x8*)&Vs[(4 + quad) * 512 + (df * 16 + l15) * 8];
      OH[df] = mfma16(v1, pH1, mfma16(v0, pH0, OH[df]));
      if (do_lo) OL[df] = mfma16(v1, pL1, mfma16(v0, pL0, OL[df]));
    }
    __syncthreads();
  }

  sumH += __shfl_xor(sumH, 16, 64); sumH += __shfl_xor(sumH, 32, 64);
  sumL += __shfl_xor(sumL, 16, 64); sumL += __shfl_xor(sumL, 32, 64);
  float invH = 1.f / sumH, invL = 1.f / sumL;

  {
    u16* op = ob + (size_t)(b * S_ + rowH) * EQ_ + h * HD_;
    #pragma unroll
    for (int df = 0; df < 4; ++df) {
      uint2 w;
      w.x = pk2(OH[df][0] * invH, OH[df][1] * invH);
      w.y = pk2(OH[df][2] * invH, OH[df][3] * invH);
      *(uint2*)(op + df * 16 + quad * 4) = w;
    }
  }
  {
    u16* op = ob + (size_t)(b * S_ + rowL) * EQ_ + h * HD_;
    #pragma unroll
    for (int df = 0; df < 4; ++df) {
      uint2 w;
      w.x = pk2(OL[df][0] * invL, OL[df][1] * invL);
      w.y = pk2(OL[df][2] * invL, OL[df][3] * invL);
      *(uint2*)(op + df * 16 + quad * 4) = w;
    }
  }
}

extern "C" void kernel_launch(void* const* d_in, const int* in_sizes, int n_in,
                              void* d_out, int out_size, void* d_ws, size_t ws_size,
                              hipStream_t stream) {
  (void)in_sizes; (void)n_in; (void)out_size; (void)ws_size;
  const float* x  = (const float*)d_in[0];
  const float* fc = (const float*)d_in[1];
  const float* wq = (const float*)d_in[2];
  const float* wk = (const float*)d_in[3];
  const float* wv = (const float*)d_in[4];
  const float* wo = (const float*)d_in[5];
  float* out = (float*)d_out;
  char* ws = (char*)d_ws;

  u16* xb  = (u16*)(ws);              // 4096x2048
  u16* wqb = (u16*)(ws + 16777216);   // 2048x2048  } contiguous fused [wq;wk;wv]
  u16* wob = (u16*)(ws + 29360128);   // 2048x2048
  u16* qb  = (u16*)(ws + 37748736);   // 4096x2048  (rope'd, x QSCALE)
  u16* kb  = (u16*)(ws + 54525952);   // 4096x512   (rope'd)
  u16* vtb = (u16*)(ws + 58720256);   // 512x4096   (V^T)
  u16* ob  = (u16*)(ws + 62914560);   // 4096x2048

  cast_all<<<18432, 256, 0, stream>>>((const float4*)x, (const float4*)wq,
                                      (const float4*)wk, (const float4*)wv,
                                      (const float4*)wo, (ushort4*)ws);

  gemm_qkv<<<dim3(32, 32), 256, 0, stream>>>(xb, wqb, qb, kb, vtb, fc);

  flash_attn<<<dim3(16, 32, 2), 256, 0, stream>>>(qb, kb, vtb, ob);

  gemm_o<<<dim3(16, 64), 256, 0, stream>>>(ob, wob, out, D_, EQ_);
}